// Round 9
// baseline (59.979 us; speedup 1.0000x reference)
//
#include <hip/hip_runtime.h>

typedef float  f32x4  __attribute__((ext_vector_type(4)));
typedef float  f32x4a __attribute__((ext_vector_type(4), aligned(4)));
typedef float  f32x2a __attribute__((ext_vector_type(2), aligned(4)));
typedef __bf16 bf16x8 __attribute__((ext_vector_type(8)));
typedef short  short8 __attribute__((ext_vector_type(8)));

#define F      65
#define NTT    17           // 16 D-tiles of 16 cols + 1 S-tile
#define KS3    3            // K padded (65 + bias) -> 96, 3 ksteps of 32
#define RPB    256          // rows per block (16 waves x 16 rows)
#define NCHUNK (NTT*KS3*64) // 3264 16B chunks (52224 B)
#define NEGL2E -1.4426950408889634f

__device__ __forceinline__ float fast_sigmoid(float x) {
  float e = __builtin_amdgcn_exp2f(NEGL2E * x);
  return __builtin_amdgcn_rcpf(1.0f + e);
}
// acc pre-scaled by -log2e: sigmoid = rcp(1 + exp2(acc))
__device__ __forceinline__ float sig_prescaled(float a) {
  return __builtin_amdgcn_rcpf(1.0f + __builtin_amdgcn_exp2f(a));
}
template<int CTRL>
__device__ __forceinline__ float dpp_mov(float v) {
  return __builtin_bit_cast(float,
    __builtin_amdgcn_update_dpp(0, __builtin_bit_cast(int, v), CTRL, 0xF, 0xF, true));
}
__device__ __forceinline__ float reduce16(float v) {
  v += dpp_mov<0xB1>(v);                   // xor1
  v += dpp_mov<0x4E>(v);                   // xor2
  v += dpp_mov<0x141>(v);                  // xor4 (row_half_mirror)
  v += dpp_mov<0x140>(v);                  // xor8 (row_mirror)
  return v;
}

// ---- prepass: fragment-ordered bf16 W blob; D-part pre-scaled by -log2e ----
// chunk = (t*3+s)*64 + lane ; lane holds 8 bf16 of B:
//   col n = 16*t + (lane&15), k = 32*s + 8*(lane>>4) + j   (k==65 is bias row)
__global__ void prep_w(const float* __restrict__ W_S, const float* __restrict__ b_S,
                       const float* __restrict__ W_D, const float* __restrict__ b_D,
                       unsigned short* __restrict__ wsb) {
  int b = blockIdx.x;              // 0..50 = t*3+s
  int t = b / 3, s = b % 3;
  int l = threadIdx.x;
  int c = l & 15, q = l >> 4;
  short8 out;
#pragma unroll
  for (int j = 0; j < 8; ++j) {
    int k = 32 * s + 8 * q + j;
    float v = 0.0f;
    if (t < 16) {
      int n = 16 * t + c;
      if (k < F)       v = NEGL2E * W_D[n * F + k];
      else if (k == F) v = NEGL2E * b_D[n];
    } else if (c < 8) {
      if (k < F)       v = W_S[c * F + k];
      else if (k == F) v = b_S[c];
    }
    unsigned int u = __builtin_bit_cast(unsigned int, v);
    u += 0x7FFFu + ((u >> 16) & 1u);
    out[j] = (short)(u >> 16);
  }
  reinterpret_cast<short8*>(wsb)[b * 64 + l] = out;
}

// ---- main: 16-row waves, 1024-thread blocks, 8 waves/SIMD target ----------
__launch_bounds__(1024, 8)  // 8 waves/EU -> unified reg cap 64; live set ~55
__global__ void mpuf_main(const float* __restrict__ phi,
                          const unsigned short* __restrict__ wsb,
                          float* __restrict__ out_ans,
                          float* __restrict__ out_rel) {
  __shared__ short8 ldsB[NCHUNK];          // 52224 B
  __shared__ float  soutv[RPB][10];        // 10240 B (pad: q-groups 8 banks apart)
  __shared__ float  mtrec[RPB][17];        // 17408 B
  // total 79872 B -> 2 blocks/CU (159744 <= 163840)

  const int tid  = threadIdx.x;
  const int wave = tid >> 6;
  const int l    = tid & 63;
  const int c    = l & 15;                 // col-in-tile / row-in-A-fragment
  const int q    = l >> 4;                 // k-group / C-row quad
  const int wrow = wave * 16;
  const int brow = blockIdx.x * RPB;

  const float* prow = phi + (size_t)(brow + wrow + c) * F;

  // phi loads first (in flight during staging)
  f32x4a f4[4];
#pragma unroll
  for (int s = 0; s < 2; ++s) {
    f4[2 * s]     = *reinterpret_cast<const f32x4a*>(prow + 32 * s + 8 * q);
    f4[2 * s + 1] = *reinterpret_cast<const f32x4a*>(prow + 32 * s + 8 * q + 4);
  }
  const float a64 = prow[64];

  // stage W blob -> LDS (coalesced, 4 rounds of 1024 threads)
  const short8* wsv = reinterpret_cast<const short8*>(wsb);
#pragma unroll
  for (int i = 0; i < 4; ++i) {
    int idx = tid + i * 1024;
    if (idx < NCHUNK) ldsB[idx] = wsv[idx];
  }

  // A -> bf16 fragments (12 VGPRs, live through whole kernel)
  bf16x8 af[3];
#pragma unroll
  for (int s = 0; s < 2; ++s) {
    bf16x8 v;
#pragma unroll
    for (int j = 0; j < 4; ++j) {
      v[j]     = (__bf16)f4[s * 2][j];
      v[j + 4] = (__bf16)f4[s * 2 + 1][j];
    }
    af[s] = v;
  }
  {
    bf16x8 v = {};
    if (q == 0) { v[0] = (__bf16)a64; v[1] = (__bf16)1.0f; }  // k=64 + bias
    af[2] = v;
  }

  __syncthreads();

  // ---- S tile (t=16, unscaled): Sdelta with bias folded --------------------
  f32x4 aS = {};
#pragma unroll
  for (int s = 0; s < KS3; ++s) {
    bf16x8 b = __builtin_bit_cast(bf16x8, ldsB[(16 * KS3 + s) * 64 + l]);
    aS = __builtin_amdgcn_mfma_f32_16x16x32_bf16(af[s], b, aS, 0, 0, 0);
  }
  // C layout 16x16: col = lane&15, row = (lane>>4)*4 + r
  if (c < 8) {
#pragma unroll
    for (int r = 0; r < 4; ++r) {
      const int R = wrow + q * 4 + r;
      out_rel[(size_t)(brow + R) * 8 + c] = fabsf(aS[r]);
      soutv[R][c] = fast_sigmoid(aS[r]);
    }
  }
  // wave-private rows: same-wave LDS producer/consumer, lgkmcnt-ordered,
  // no barrier (pattern verified R4-R8).

  // ---- per-row records: Ml (bits 0-3) in regs, Mt (bits 4-7) into LDS ------
  float Ml[4];
#pragma unroll
  for (int r = 0; r < 4; ++r) {
    const int R = wrow + q * 4 + r;
    f32x2a p01 = *reinterpret_cast<const f32x2a*>(&soutv[R][0]);
    f32x2a p23 = *reinterpret_cast<const f32x2a*>(&soutv[R][2]);
    f32x2a p45 = *reinterpret_cast<const f32x2a*>(&soutv[R][4]);
    f32x2a p67 = *reinterpret_cast<const f32x2a*>(&soutv[R][6]);
    float m = 0.99999f;
    m *= (c & 1) ? p01[0] : 1.0f - p01[0];
    m *= (c & 2) ? p01[1] : 1.0f - p01[1];
    m *= (c & 4) ? p23[0] : 1.0f - p23[0];
    m *= (c & 8) ? p23[1] : 1.0f - p23[1];
    Ml[r] = m;
    float mt = (c & 1) ? p45[0] : 1.0f - p45[0];
    mt *= (c & 2) ? p45[1] : 1.0f - p45[1];
    mt *= (c & 4) ? p67[0] : 1.0f - p67[0];
    mt *= (c & 8) ? p67[1] : 1.0f - p67[1];
    mtrec[R][c] = mt;
  }

  float ans[4] = {0, 0, 0, 0};

  // ---- D phase: 16 tiles fully unrolled, imm-offset ds reads ---------------
#pragma unroll
  for (int t = 0; t < 16; ++t) {
    f32x4 A = {};
#pragma unroll
    for (int s = 0; s < KS3; ++s) {
      bf16x8 b = __builtin_bit_cast(bf16x8, ldsB[(t * KS3 + s) * 64 + l]);
      A = __builtin_amdgcn_mfma_f32_16x16x32_bf16(af[s], b, A, 0, 0, 0);
    }
#pragma unroll
    for (int r = 0; r < 4; ++r) {
      const int R = wrow + q * 4 + r;
      ans[r] = fmaf(sig_prescaled(A[r]), mtrec[R][t], ans[r]);
    }
  }

  // ---- apply Ml, 16-lane DPP reduce, vectorized store ----------------------
#pragma unroll
  for (int r = 0; r < 4; ++r) ans[r] = reduce16(Ml[r] * ans[r]);
  if (c == 0) {
    f32x4 o = { ans[0], ans[1], ans[2], ans[3] };
    *reinterpret_cast<f32x4*>(&out_ans[brow + wrow + q * 4]) = o;
  }
}

extern "C" void kernel_launch(void* const* d_in, const int* in_sizes, int n_in,
                              void* d_out, int out_size, void* d_ws, size_t ws_size,
                              hipStream_t stream) {
  const float* phi = (const float*)d_in[0];
  const float* W_S = (const float*)d_in[1];
  const float* b_S = (const float*)d_in[2];
  const float* W_D = (const float*)d_in[3];
  const float* b_D = (const float*)d_in[4];
  const int rows = in_sizes[0] / F;        // 262144
  unsigned short* wsb = (unsigned short*)d_ws;   // 52224 B used
  float* out_ans = (float*)d_out;
  float* out_rel = out_ans + rows;
  hipLaunchKernelGGL(prep_w, dim3(NTT * KS3), dim3(64), 0, stream,
                     W_S, b_S, W_D, b_D, wsb);
  hipLaunchKernelGGL(mpuf_main, dim3(rows / RPB), dim3(1024), 0, stream,
                     phi, wsb, out_ans, out_rel);
}

// Round 10
// 39.942 us; speedup vs baseline: 1.5017x; 1.5017x over previous
//
#include <hip/hip_runtime.h>

typedef float  f32x4  __attribute__((ext_vector_type(4)));
typedef float  f32x4a __attribute__((ext_vector_type(4), aligned(4)));
typedef float  f32x2  __attribute__((ext_vector_type(2)));
typedef __bf16 bf16x8 __attribute__((ext_vector_type(8)));
typedef short  short8 __attribute__((ext_vector_type(8)));

#define F      65
#define NTT    17           // 16 D-tiles of 16 cols + 1 S-tile
#define KS3    3            // K padded (65 + bias) -> 96, 3 ksteps of 32
#define RPW    64           // rows per wave (4 x 16-row fragments)
#define RPB    256          // rows per block (4 waves x 64 rows)
#define NEGL2E -1.4426950408889634f

__device__ __forceinline__ float fast_sigmoid(float x) {
  float e = __builtin_amdgcn_exp2f(NEGL2E * x);
  return __builtin_amdgcn_rcpf(1.0f + e);
}
// acc pre-scaled by -log2e: sigmoid = rcp(1 + exp2(acc))
__device__ __forceinline__ float sig_prescaled(float a) {
  return __builtin_amdgcn_rcpf(1.0f + __builtin_amdgcn_exp2f(a));
}
template<int CTRL>
__device__ __forceinline__ float dpp_mov(float v) {
  return __builtin_bit_cast(float,
    __builtin_amdgcn_update_dpp(0, __builtin_bit_cast(int, v), CTRL, 0xF, 0xF, true));
}
__device__ __forceinline__ float reduce16(float v) {
  v += dpp_mov<0xB1>(v);                   // xor1
  v += dpp_mov<0x4E>(v);                   // xor2
  v += dpp_mov<0x141>(v);                  // xor4 (row_half_mirror)
  v += dpp_mov<0x140>(v);                  // xor8 (row_mirror)
  return v;
}

// ---- prepass: fragment-ordered bf16 W blob; D-part pre-scaled by -log2e ----
// chunk = (t*3+s)*64 + lane ; lane holds 8 bf16 of B:
//   col n = 16*t + (lane&15), k = 32*s + 8*(lane>>4) + j   (k==65 is bias row)
__global__ void prep_w(const float* __restrict__ W_S, const float* __restrict__ b_S,
                       const float* __restrict__ W_D, const float* __restrict__ b_D,
                       unsigned short* __restrict__ wsb) {
  int b = blockIdx.x;              // 0..50 = t*3+s
  int t = b / 3, s = b % 3;
  int l = threadIdx.x;
  int c = l & 15, q = l >> 4;
  short8 out;
#pragma unroll
  for (int j = 0; j < 8; ++j) {
    int k = 32 * s + 8 * q + j;
    float v = 0.0f;
    if (t < 16) {
      int n = 16 * t + c;
      if (k < F)       v = NEGL2E * W_D[n * F + k];
      else if (k == F) v = NEGL2E * b_D[n];
    } else if (c < 8) {
      if (k < F)       v = W_S[c * F + k];
      else if (k == F) v = b_S[c];
    }
    unsigned int u = __builtin_bit_cast(unsigned int, v);
    u += 0x7FFFu + ((u >> 16) & 1u);
    out[j] = (short)(u >> 16);
  }
  reinterpret_cast<short8*>(wsb)[b * 64 + l] = out;
}

// ---- main: 64-row waves -> B reads amortized over 4 fragments --------------
__launch_bounds__(256, 3)   // 3 waves/EU -> reg cap ~170; live ~120 (no spill)
__global__ void mpuf_main(const float* __restrict__ phi,
                          const unsigned short* __restrict__ wsb,
                          float* __restrict__ out_ans,
                          float* __restrict__ out_rel) {
  __shared__ float soutv[RPB][10];         // 10240 B : f32 souts per row
  __shared__ float mtrec[RPB][20];         // 20480 B : Mt per (row, t)

  const int tid  = threadIdx.x;
  const int wave = tid >> 6;
  const int l    = tid & 63;
  const int c    = l & 15;                 // col-in-tile / row-in-A-fragment
  const int q    = l >> 4;                 // k-group / C-row quad
  const int wrow = wave * RPW;
  const int brow = blockIdx.x * RPB;

  // ---- phi loads for 4 fragments (issued first; HBM latency) ---------------
  f32x4a f4[4][4];
  float  a64[4];
#pragma unroll
  for (int h = 0; h < 4; ++h) {
    const float* prow = phi + (size_t)(brow + wrow + 16 * h + c) * F;
#pragma unroll
    for (int s = 0; s < 2; ++s) {
      f4[h][2 * s]     = *reinterpret_cast<const f32x4a*>(prow + 32 * s + 8 * q);
      f4[h][2 * s + 1] = *reinterpret_cast<const f32x4a*>(prow + 32 * s + 8 * q + 4);
    }
    a64[h] = prow[64];
  }

  // B prefetch: S-tile + tile 0 (blob is L2-resident, shared by all waves)
  const short8* wsv = reinterpret_cast<const short8*>(wsb);
  short8 bS[3], bcur[3], bnxt[3];
#pragma unroll
  for (int s = 0; s < 3; ++s) bS[s]   = wsv[(16 * KS3 + s) * 64 + l];
#pragma unroll
  for (int s = 0; s < 3; ++s) bcur[s] = wsv[s * 64 + l];

  // A -> bf16 fragments (48 VGPRs, live through whole kernel)
  bf16x8 af[4][3];
#pragma unroll
  for (int h = 0; h < 4; ++h) {
#pragma unroll
    for (int s = 0; s < 2; ++s) {
      bf16x8 v;
#pragma unroll
      for (int j = 0; j < 4; ++j) {
        v[j]     = (__bf16)f4[h][2 * s][j];
        v[j + 4] = (__bf16)f4[h][2 * s + 1][j];
      }
      af[h][s] = v;
    }
    bf16x8 v = {};
    if (q == 0) { v[0] = (__bf16)a64[h]; v[1] = (__bf16)1.0f; }  // k=64 + bias
    af[h][2] = v;
  }

  // ---- S tile (unscaled): Sdelta with bias folded, 4 fragments -------------
  f32x4 aS[4] = {{}, {}, {}, {}};
#pragma unroll
  for (int s = 0; s < KS3; ++s) {
    bf16x8 b = __builtin_bit_cast(bf16x8, bS[s]);
#pragma unroll
    for (int h = 0; h < 4; ++h)
      aS[h] = __builtin_amdgcn_mfma_f32_16x16x32_bf16(af[h][s], b, aS[h], 0, 0, 0);
  }
  // C layout 16x16: col = lane&15, row = (lane>>4)*4 + r
  if (c < 8) {
#pragma unroll
    for (int h = 0; h < 4; ++h)
#pragma unroll
      for (int r = 0; r < 4; ++r) {
        const int R = wrow + 16 * h + q * 4 + r;
        out_rel[(size_t)(brow + R) * 8 + c] = fabsf(aS[h][r]);
        soutv[R][c] = fast_sigmoid(aS[h][r]);
      }
  }
  // wave-private rows: same-wave LDS producer/consumer, lgkmcnt-ordered,
  // no barrier (pattern verified R4-R9).

  // ---- per-row Mt (bits 4-7 of d, tile t = c) into LDS ---------------------
#pragma unroll
  for (int h = 0; h < 4; ++h)
#pragma unroll
    for (int r = 0; r < 4; ++r) {
      const int R = wrow + 16 * h + q * 4 + r;
      f32x2 p45 = *reinterpret_cast<const f32x2*>(&soutv[R][4]);
      f32x2 p67 = *reinterpret_cast<const f32x2*>(&soutv[R][6]);
      float mt = (c & 1) ? p45[0] : 1.0f - p45[0];
      mt *= (c & 2) ? p45[1] : 1.0f - p45[1];
      mt *= (c & 4) ? p67[0] : 1.0f - p67[0];
      mt *= (c & 8) ? p67[1] : 1.0f - p67[1];
      mtrec[R][c] = mt;
    }

  float ans[4][4];
#pragma unroll
  for (int h = 0; h < 4; ++h)
#pragma unroll
    for (int r = 0; r < 4; ++r) ans[h][r] = 0.0f;

  // ---- D loop: 16 tiles, one-tile-ahead B prefetch, 4 fragments ------------
#pragma unroll 1
  for (int t = 0; t < 16; ++t) {
    const int tn = (t < 15) ? t + 1 : 15;
#pragma unroll
    for (int s = 0; s < 3; ++s) bnxt[s] = wsv[(tn * KS3 + s) * 64 + l];
    f32x4 A[4] = {{}, {}, {}, {}};
#pragma unroll
    for (int s = 0; s < KS3; ++s) {
      bf16x8 b = __builtin_bit_cast(bf16x8, bcur[s]);
#pragma unroll
      for (int h = 0; h < 4; ++h)
        A[h] = __builtin_amdgcn_mfma_f32_16x16x32_bf16(af[h][s], b, A[h], 0, 0, 0);
    }
#pragma unroll
    for (int h = 0; h < 4; ++h)
#pragma unroll
      for (int r = 0; r < 4; ++r) {
        const int R = wrow + 16 * h + q * 4 + r;
        ans[h][r] = fmaf(sig_prescaled(A[h][r]), mtrec[R][t], ans[h][r]);
      }
#pragma unroll
    for (int s = 0; s < 3; ++s) bcur[s] = bnxt[s];
  }

  // ---- epilogue: Ml recompute (af regs dead), reduce, store ----------------
#pragma unroll
  for (int h = 0; h < 4; ++h) {
    f32x4 o;
#pragma unroll
    for (int r = 0; r < 4; ++r) {
      const int R = wrow + 16 * h + q * 4 + r;
      f32x2 p01 = *reinterpret_cast<const f32x2*>(&soutv[R][0]);
      f32x2 p23 = *reinterpret_cast<const f32x2*>(&soutv[R][2]);
      float m = 0.99999f;
      m *= (c & 1) ? p01[0] : 1.0f - p01[0];
      m *= (c & 2) ? p01[1] : 1.0f - p01[1];
      m *= (c & 4) ? p23[0] : 1.0f - p23[0];
      m *= (c & 8) ? p23[1] : 1.0f - p23[1];
      o[r] = reduce16(m * ans[h][r]);
    }
    if (c == 0)
      *reinterpret_cast<f32x4*>(&out_ans[brow + wrow + 16 * h + q * 4]) = o;
  }
}

extern "C" void kernel_launch(void* const* d_in, const int* in_sizes, int n_in,
                              void* d_out, int out_size, void* d_ws, size_t ws_size,
                              hipStream_t stream) {
  const float* phi = (const float*)d_in[0];
  const float* W_S = (const float*)d_in[1];
  const float* b_S = (const float*)d_in[2];
  const float* W_D = (const float*)d_in[3];
  const float* b_D = (const float*)d_in[4];
  const int rows = in_sizes[0] / F;        // 262144
  unsigned short* wsb = (unsigned short*)d_ws;   // 52224 B used
  float* out_ans = (float*)d_out;
  float* out_rel = out_ans + rows;
  hipLaunchKernelGGL(prep_w, dim3(NTT * KS3), dim3(64), 0, stream,
                     W_S, b_S, W_D, b_D, wsb);
  hipLaunchKernelGGL(mpuf_main, dim3(rows / RPB), dim3(256), 0, stream,
                     phi, wsb, out_ans, out_rel);
}